// Round 2
// baseline (841.650 us; speedup 1.0000x reference)
//
#include <hip/hip_runtime.h>
#include <hip/hip_bf16.h>

#define NN 4096
typedef unsigned short u16;
typedef __bf16 bf16x8 __attribute__((ext_vector_type(8)));
typedef float f32x4 __attribute__((ext_vector_type(4)));

typedef const __attribute__((address_space(1))) void* gptr_t;
typedef __attribute__((address_space(3))) void* lptr_t;

// ---------------- block reduction helper (256 threads / 4 waves) ----------------
__device__ inline float block_sum(float v, volatile float* sbuf) {
    int lane = threadIdx.x & 63, wv = threadIdx.x >> 6;
#pragma unroll
    for (int o = 32; o > 0; o >>= 1) v += __shfl_xor(v, o, 64);
    if (lane == 0) sbuf[wv] = v;
    __syncthreads();
    float r = sbuf[0] + sbuf[1] + sbuf[2] + sbuf[3];
    __syncthreads();
    return r;
}

// ---------------- normalize rows, emit bf16 + sum-of-squares(bf16) ----------------
template <int D>
__global__ void normalize_kernel(const float* __restrict__ in, u16* __restrict__ outb,
                                 float* __restrict__ ssout) {
    __shared__ float sbuf[4];
    int row = blockIdx.x;
    const float* x = in + (size_t)row * D;
    float s = 0.f;
    for (int j = threadIdx.x; j < D; j += 256) { float v = x[j]; s += v * v; }
    float tot = block_sum(s, sbuf);
    float nrm = fmaxf(sqrtf(tot), 1e-12f);
    float sb = 0.f;
    for (int j = threadIdx.x; j < D; j += 256) {
        float v = x[j] / nrm;
        __bf16 h = (__bf16)v;
        outb[(size_t)row * D + j] = *(const u16*)&h;
        float vb = (float)h;
        sb += vb * vb;
    }
    float totb = block_sum(sb, sbuf);
    if (threadIdx.x == 0) ssout[row] = totb;
}

// ---------------- Gram -> distance transform (MODE 0: W_P=exp(-d2); MODE 1: dist + rowsum) ----------------
template <int K, int MODE>
__launch_bounds__(256)
__global__ void gram_kernel(const u16* __restrict__ X, const float* __restrict__ ss,
                            float* __restrict__ out, float* __restrict__ rowsum) {
    __shared__ __align__(16) u16 lA[128 * 32];
    __shared__ __align__(16) u16 lB[128 * 32];
    const int tid = threadIdx.x;
    const int wv = tid >> 6, lane = tid & 63;
    const int wr = wv >> 1, wc = wv & 1;
    const int brow = blockIdx.y * 128, bcol = blockIdx.x * 128;
    const int r = lane & 15, kc = lane >> 4;
    const int crow = lane >> 2;          // staging: row within 16-row chunk
    const int koff = (lane & 3) * 8;     // staging: element offset (16B granule)

    f32x4 acc[4][4];
#pragma unroll
    for (int mi = 0; mi < 4; ++mi)
#pragma unroll
        for (int ni = 0; ni < 4; ++ni) acc[mi][ni] = (f32x4){0.f, 0.f, 0.f, 0.f};

    for (int k0 = 0; k0 < K; k0 += 32) {
        __syncthreads();  // protect LDS from readers of previous step
        // 128 rows = 8 chunks of 16 rows; 8 chunks for A + 8 for B over 4 waves
#pragma unroll
        for (int cc = 0; cc < 2; ++cc) {
            int c = wv * 2 + cc;  // c in [0,8)
            const u16* ga = X + (size_t)(brow + c * 16 + crow) * K + k0 + koff;
            const u16* gb = X + (size_t)(bcol + c * 16 + crow) * K + k0 + koff;
            __builtin_amdgcn_global_load_lds((gptr_t)ga, (lptr_t)&lA[c * 512], 16, 0, 0);
            __builtin_amdgcn_global_load_lds((gptr_t)gb, (lptr_t)&lB[c * 512], 16, 0, 0);
        }
        __syncthreads();  // compiler drains vmcnt before barrier

        bf16x8 af[4], bfr[4];
#pragma unroll
        for (int mi = 0; mi < 4; ++mi)
            af[mi] = *(const bf16x8*)&lA[(wr * 64 + mi * 16 + r) * 32 + kc * 8];
#pragma unroll
        for (int ni = 0; ni < 4; ++ni)
            bfr[ni] = *(const bf16x8*)&lB[(wc * 64 + ni * 16 + r) * 32 + kc * 8];
#pragma unroll
        for (int mi = 0; mi < 4; ++mi)
#pragma unroll
            for (int ni = 0; ni < 4; ++ni)
                acc[mi][ni] = __builtin_amdgcn_mfma_f32_16x16x32_bf16(af[mi], bfr[ni], acc[mi][ni], 0, 0, 0);
    }

    // epilogue: C/D layout col=lane&15, row=(lane>>4)*4+reg  [guide-verified]
    const int q = lane >> 4;
#pragma unroll
    for (int mi = 0; mi < 4; ++mi) {
#pragma unroll
        for (int v = 0; v < 4; ++v) {
            int row = brow + wr * 64 + mi * 16 + q * 4 + v;
            float ssi = ss[row];
            float rs = 0.f;
#pragma unroll
            for (int ni = 0; ni < 4; ++ni) {
                int col = bcol + wc * 64 + ni * 16 + r;
                float d2 = fmaxf(ssi + ss[col] - 2.0f * acc[mi][ni][v], 0.f);
                float o = (MODE == 0) ? __expf(-d2) : sqrtf(d2);
                out[(size_t)row * NN + col] = o;
                rs += o;
            }
            if (MODE == 1) {
#pragma unroll
                for (int o2 = 1; o2 < 16; o2 <<= 1) rs += __shfl_xor(rs, o2, 64);
                if (r == 0) atomicAdd(&rowsum[row], rs);
            }
        }
    }
}

// ---------------- top-10 per row of W_P with same-id override, tie: lower index first ----------------
__global__ void topk_kernel(const float* __restrict__ WP, const int* __restrict__ idx,
                            int* __restrict__ topk) {
    __shared__ unsigned long long sred[4];
    __shared__ unsigned long long sbest;
    int row = blockIdx.x, tid = threadIdx.x;
    int myid = idx[row];
    unsigned key[16];
#pragma unroll
    for (int a = 0; a < 16; ++a) {
        int j = tid + a * 256;
        float w = WP[(size_t)row * NN + j];
        if (idx[j] == myid) w = 1.0f;
        key[a] = __float_as_uint(w);  // w > 0 always -> monotonic as uint
    }
    int lane = tid & 63, wv = tid >> 6;
    for (int it = 0; it < 10; ++it) {
        unsigned long long best = 0;
#pragma unroll
        for (int a = 0; a < 16; ++a) {
            unsigned long long pk =
                ((unsigned long long)key[a] << 32) | (unsigned)(0xFFFFFFFFu - (unsigned)(tid + a * 256));
            if (pk > best) best = pk;
        }
#pragma unroll
        for (int o = 32; o > 0; o >>= 1) {
            unsigned long long t = __shfl_xor(best, o, 64);
            if (t > best) best = t;
        }
        if (lane == 0) sred[wv] = best;
        __syncthreads();
        if (tid == 0) {
            unsigned long long b = sred[0];
            for (int w2 = 1; w2 < 4; ++w2)
                if (sred[w2] > b) b = sred[w2];
            sbest = b;
        }
        __syncthreads();
        unsigned jstar = 0xFFFFFFFFu - (unsigned)(sbest & 0xFFFFFFFFu);
        if (tid == 0) topk[row * 10 + it] = (int)jstar;
        if ((jstar & 255u) == (unsigned)tid) key[jstar >> 8] = 0u;
        __syncthreads();
    }
}

// ---------------- mutual-kNN adjacency (V), degree ----------------
__global__ void mutual_kernel(const int* __restrict__ topk, int* __restrict__ nbr,
                              int* __restrict__ deg) {
    int i = blockIdx.x * 256 + threadIdx.x;
    if (i >= NN) return;
    int t[10];
#pragma unroll
    for (int a = 0; a < 10; ++a) t[a] = topk[i * 10 + a];
    int d = 0;
    for (int a = 0; a < 10; ++a) {
        int j = t[a];
        bool mut = false;
        for (int b = 0; b < 10; ++b) mut = mut || (topk[j * 10 + b] == i);
        if (mut) { nbr[i * 10 + d] = j; d++; }
    }
    deg[i] = d;
}

// ---------------- W_C_tilda sparse: VV[m][j]=|nbr(m) ∩ nbr(j)| / max(deg[m],1) ----------------
__global__ void tilda_kernel(const int* __restrict__ nbr, const int* __restrict__ deg,
                             float* __restrict__ tvals) {
    int m = blockIdx.x * 256 + threadIdx.x;
    if (m >= NN) return;
    int dm = deg[m];
    int a_[10];
    for (int a = 0; a < dm; ++a) a_[a] = nbr[m * 10 + a];
    float dv = (float)(dm > 1 ? dm : 1);
    for (int a = 0; a < dm; ++a) {
        int j = a_[a];
        int dj = deg[j];
        int cnt = 0;
        for (int p = 0; p < dm; ++p) {
            int np = a_[p];
            for (int qq = 0; qq < dj; ++qq) cnt += (nbr[j * 10 + qq] == np) ? 1 : 0;
        }
        tvals[m * 10 + a] = (float)cnt / dv;
    }
}

// ---------------- W_C_hat sparse: mean of 5 tilda rows (topk half) ----------------
__global__ void hat_kernel(const int* __restrict__ topk, const int* __restrict__ nbr,
                           const int* __restrict__ deg, const float* __restrict__ tvals,
                           int* __restrict__ hcols, float* __restrict__ hvals,
                           int* __restrict__ hcnt) {
    int i = blockIdx.x * 256 + threadIdx.x;
    if (i >= NN) return;
    int cols[50];
    float vals[50];
    int c = 0;
    for (int h = 0; h < 5; ++h) {
        int m = topk[i * 10 + h];
        int dm = deg[m];
        for (int a = 0; a < dm; ++a) {
            int j = nbr[m * 10 + a];
            float v = tvals[m * 10 + a];
            int f = -1;
            for (int p = 0; p < c; ++p)
                if (cols[p] == j) { f = p; break; }
            if (f >= 0) vals[f] += v;
            else { cols[c] = j; vals[c] = v; ++c; }
        }
    }
    hcnt[i] = c;
    for (int p = 0; p < c; ++p) {
        hcols[i * 50 + p] = cols[p];
        hvals[i * 50 + p] = vals[p] / 5.0f;
    }
}

// ---------------- per-row inv-mean + logsumexp(-S_norm) for both S matrices ----------------
__global__ void lse_kernel(const float* __restrict__ Sf, const float* __restrict__ Sg,
                           const float* __restrict__ rsf, const float* __restrict__ rsg,
                           float* __restrict__ invmf, float* __restrict__ invmg,
                           float* __restrict__ lsef, float* __restrict__ lseg) {
    __shared__ float sbuf[4];
    int row = blockIdx.x;
    float imf = (float)NN / rsf[row];
    float img = (float)NN / rsg[row];
    float ef = 0.f, eg = 0.f;
    for (int j = threadIdx.x; j < NN; j += 256) {
        ef += __expf(-Sf[(size_t)row * NN + j] * imf);
        eg += __expf(-Sg[(size_t)row * NN + j] * img);
    }
    float tf = block_sum(ef, sbuf);
    float tg = block_sum(eg, sbuf);
    if (threadIdx.x == 0) {
        invmf[row] = imf;
        invmg[row] = img;
        lsef[row] = logf(tf);
        lseg[row] = logf(tg);
    }
}

// ---------------- fused dense pass: RC dense terms (W_P part) + KL ----------------
__global__ void final_dense_kernel(const float* __restrict__ Sf, const float* __restrict__ Sg,
                                   const float* __restrict__ WP, const float* __restrict__ invmf,
                                   const float* __restrict__ invmg, const float* __restrict__ lsef,
                                   const float* __restrict__ lseg, double* __restrict__ acc) {
    __shared__ float sbuf[4];
    int row = blockIdx.x;
    float imf = invmf[row], img = invmg[row], lf = lsef[row], lg = lseg[row];
    float af = 0.f, ag = 0.f, akl = 0.f;
    for (int j = threadIdx.x; j < NN; j += 256) {
        size_t o = (size_t)row * NN + j;
        float sf = Sf[o] * imf;
        float sg = Sg[o] * img;
        float wp = WP[o];
        if (j != row) {
            float t = fmaxf(1.f - sf, 0.f);
            float pu = t * t;
            float gq = sf * sf - pu;
            af += pu + 0.5f * gq * wp;
            t = fmaxf(1.f - sg, 0.f);
            pu = t * t;
            gq = sg * sg - pu;
            ag += pu + 0.5f * gq * wp;
        }
        float lq = -sf - lf;
        float lp = -sg - lg;
        float pp = __expf(lp);
        akl += pp * (lp - lq);
    }
    float tf = block_sum(af, sbuf);
    float tg2 = block_sum(ag, sbuf);
    float tk = block_sum(akl, sbuf);
    if (threadIdx.x == 0) {
        atomicAdd(&acc[0], (double)tf);
        atomicAdd(&acc[1], (double)tg2);
        atomicAdd(&acc[2], (double)tk);
    }
}

// ---------------- sparse W_C correction: sum H_ij*(g_ij+g_ji)/4 ----------------
__global__ void sparse_kernel(const float* __restrict__ Sf, const float* __restrict__ Sg,
                              const int* __restrict__ hcols, const float* __restrict__ hvals,
                              const int* __restrict__ hcnt, const float* __restrict__ invmf,
                              const float* __restrict__ invmg, double* __restrict__ acc) {
    int i = blockIdx.x * 256 + threadIdx.x;
    if (i >= NN) return;
    float cf = 0.f, cg = 0.f;
    float imfi = invmf[i], imgi = invmg[i];
    int c = hcnt[i];
    for (int p = 0; p < c; ++p) {
        int j = hcols[i * 50 + p];
        if (j == i) continue;
        float v = hvals[i * 50 + p];
        float s1 = Sf[(size_t)i * NN + j] * imfi;
        float s2 = Sf[(size_t)j * NN + i] * invmf[j];
        float t1 = fmaxf(1.f - s1, 0.f), t2 = fmaxf(1.f - s2, 0.f);
        cf += v * ((s1 * s1 - t1 * t1) + (s2 * s2 - t2 * t2));
        s1 = Sg[(size_t)i * NN + j] * imgi;
        s2 = Sg[(size_t)j * NN + i] * invmg[j];
        t1 = fmaxf(1.f - s1, 0.f);
        t2 = fmaxf(1.f - s2, 0.f);
        cg += v * ((s1 * s1 - t1 * t1) + (s2 * s2 - t2 * t2));
    }
    if (cf != 0.f || cg != 0.f) {
        atomicAdd(&acc[0], (double)(0.25f * cf));
        atomicAdd(&acc[1], (double)(0.25f * cg));
    }
}

__global__ void finalize_kernel(const double* __restrict__ acc, float* __restrict__ out) {
    if (threadIdx.x == 0) {
        double denom = (double)NN * (double)(NN - 1);
        double rcf = acc[0] / denom, rcg = acc[1] / denom;
        double rc = 0.5 * (rcf + rcg);
        double kl = acc[2] / (double)NN;
        out[0] = (float)rc;
        out[1] = (float)kl;
        out[2] = (float)(rc + kl);
    }
}

extern "C" void kernel_launch(void* const* d_in, const int* in_sizes, int n_in, void* d_out,
                              int out_size, void* d_ws, size_t ws_size, hipStream_t stream) {
    const float* s_f = (const float*)d_in[0];
    const float* s_g = (const float*)d_in[1];
    const float* t_g = (const float*)d_in[2];
    const int* idx = (const int*)d_in[3];
    float* out = (float*)d_out;

    char* base = (char*)d_ws;
    size_t off = 0;
    auto alloc = [&](size_t b) {
        char* p = base + off;
        off = (off + b + 255) & ~(size_t)255;
        return p;
    };
    double* acc = (double*)alloc(64);
    float* rowsum_f = (float*)alloc(NN * 4);
    float* rowsum_g = (float*)alloc(NN * 4);
    size_t zero_bytes = off;  // acc + rowsums zeroed each call
    u16* tb = (u16*)alloc((size_t)NN * 1024 * 2);
    u16* fb = (u16*)alloc((size_t)NN * 512 * 2);
    u16* gb = (u16*)alloc((size_t)NN * 512 * 2);
    float* ss_t = (float*)alloc(NN * 4);
    float* ss_f = (float*)alloc(NN * 4);
    float* ss_g = (float*)alloc(NN * 4);
    float* WP = (float*)alloc((size_t)NN * NN * 4);
    float* Sf = (float*)alloc((size_t)NN * NN * 4);
    float* Sg = (float*)alloc((size_t)NN * NN * 4);
    int* topk = (int*)alloc(NN * 10 * 4);
    int* nbr = (int*)alloc(NN * 10 * 4);
    int* deg = (int*)alloc(NN * 4);
    float* tvals = (float*)alloc(NN * 10 * 4);
    int* hcols = (int*)alloc(NN * 50 * 4);
    float* hvals = (float*)alloc(NN * 50 * 4);
    int* hcnt = (int*)alloc(NN * 4);
    float* invmf = (float*)alloc(NN * 4);
    float* invmg = (float*)alloc(NN * 4);
    float* lsef = (float*)alloc(NN * 4);
    float* lseg = (float*)alloc(NN * 4);

    hipMemsetAsync(d_ws, 0, zero_bytes, stream);

    normalize_kernel<1024><<<NN, 256, 0, stream>>>(t_g, tb, ss_t);
    normalize_kernel<512><<<NN, 256, 0, stream>>>(s_f, fb, ss_f);
    normalize_kernel<512><<<NN, 256, 0, stream>>>(s_g, gb, ss_g);

    gram_kernel<1024, 0><<<dim3(32, 32), 256, 0, stream>>>(tb, ss_t, WP, nullptr);
    gram_kernel<512, 1><<<dim3(32, 32), 256, 0, stream>>>(fb, ss_f, Sf, rowsum_f);
    gram_kernel<512, 1><<<dim3(32, 32), 256, 0, stream>>>(gb, ss_g, Sg, rowsum_g);

    topk_kernel<<<NN, 256, 0, stream>>>(WP, idx, topk);
    mutual_kernel<<<16, 256, 0, stream>>>(topk, nbr, deg);
    tilda_kernel<<<16, 256, 0, stream>>>(nbr, deg, tvals);
    hat_kernel<<<16, 256, 0, stream>>>(topk, nbr, deg, tvals, hcols, hvals, hcnt);

    lse_kernel<<<NN, 256, 0, stream>>>(Sf, Sg, rowsum_f, rowsum_g, invmf, invmg, lsef, lseg);
    final_dense_kernel<<<NN, 256, 0, stream>>>(Sf, Sg, WP, invmf, invmg, lsef, lseg, acc);
    sparse_kernel<<<16, 256, 0, stream>>>(Sf, Sg, hcols, hvals, hcnt, invmf, invmg, acc);
    finalize_kernel<<<1, 64, 0, stream>>>(acc, out);
}

// Round 3
// 316.017 us; speedup vs baseline: 2.6633x; 2.6633x over previous
//
#include <hip/hip_runtime.h>
#include <hip/hip_bf16.h>

#define NN 4096
typedef unsigned short u16;
typedef __bf16 bf16x8 __attribute__((ext_vector_type(8)));
typedef float f32x4 __attribute__((ext_vector_type(4)));

typedef const __attribute__((address_space(1))) void* gptr_t;
typedef __attribute__((address_space(3))) void* lptr_t;

// ---------------- block reduction helper (256 threads / 4 waves) ----------------
__device__ inline float block_sum(float v, volatile float* sbuf) {
    int lane = threadIdx.x & 63, wv = threadIdx.x >> 6;
#pragma unroll
    for (int o = 32; o > 0; o >>= 1) v += __shfl_xor(v, o, 64);
    if (lane == 0) sbuf[wv] = v;
    __syncthreads();
    float r = sbuf[0] + sbuf[1] + sbuf[2] + sbuf[3];
    __syncthreads();
    return r;
}

// ---------------- normalize rows, emit bf16 + sum-of-squares(bf16) ----------------
template <int D>
__global__ void normalize_kernel(const float* __restrict__ in, u16* __restrict__ outb,
                                 float* __restrict__ ssout) {
    __shared__ float sbuf[4];
    int row = blockIdx.x;
    const float* x = in + (size_t)row * D;
    float s = 0.f;
    for (int j = threadIdx.x; j < D; j += 256) { float v = x[j]; s += v * v; }
    float tot = block_sum(s, sbuf);
    float nrm = fmaxf(sqrtf(tot), 1e-12f);
    float sb = 0.f;
    for (int j = threadIdx.x; j < D; j += 256) {
        float v = x[j] / nrm;
        __bf16 h = (__bf16)v;
        outb[(size_t)row * D + j] = *(const u16*)&h;
        float vb = (float)h;
        sb += vb * vb;
    }
    float totb = block_sum(sb, sbuf);
    if (threadIdx.x == 0) ssout[row] = totb;
}

// ---------------- Gram -> distance transform (MODE 0: W_P=exp(-d2); MODE 1: dist + rowsum) ----------------
template <int K, int MODE>
__launch_bounds__(256)
__global__ void gram_kernel(const u16* __restrict__ X, const float* __restrict__ ss,
                            float* __restrict__ out, float* __restrict__ rowsum) {
    __shared__ __align__(16) u16 lA[128 * 32];
    __shared__ __align__(16) u16 lB[128 * 32];
    const int tid = threadIdx.x;
    const int wv = tid >> 6, lane = tid & 63;
    const int wr = wv >> 1, wc = wv & 1;
    const int brow = blockIdx.y * 128, bcol = blockIdx.x * 128;
    const int r = lane & 15, kc = lane >> 4;
    const int crow = lane >> 2;          // staging: row within 16-row chunk
    const int koff = (lane & 3) * 8;     // staging: element offset (16B granule)

    f32x4 acc[4][4];
#pragma unroll
    for (int mi = 0; mi < 4; ++mi)
#pragma unroll
        for (int ni = 0; ni < 4; ++ni) acc[mi][ni] = (f32x4){0.f, 0.f, 0.f, 0.f};

    for (int k0 = 0; k0 < K; k0 += 32) {
        __syncthreads();  // protect LDS from readers of previous step
        // 128 rows = 8 chunks of 16 rows; 8 chunks for A + 8 for B over 4 waves
#pragma unroll
        for (int cc = 0; cc < 2; ++cc) {
            int c = wv * 2 + cc;  // c in [0,8)
            const u16* ga = X + (size_t)(brow + c * 16 + crow) * K + k0 + koff;
            const u16* gb = X + (size_t)(bcol + c * 16 + crow) * K + k0 + koff;
            __builtin_amdgcn_global_load_lds((gptr_t)ga, (lptr_t)&lA[c * 512], 16, 0, 0);
            __builtin_amdgcn_global_load_lds((gptr_t)gb, (lptr_t)&lB[c * 512], 16, 0, 0);
        }
        __syncthreads();  // compiler drains vmcnt before barrier

        bf16x8 af[4], bfr[4];
#pragma unroll
        for (int mi = 0; mi < 4; ++mi)
            af[mi] = *(const bf16x8*)&lA[(wr * 64 + mi * 16 + r) * 32 + kc * 8];
#pragma unroll
        for (int ni = 0; ni < 4; ++ni)
            bfr[ni] = *(const bf16x8*)&lB[(wc * 64 + ni * 16 + r) * 32 + kc * 8];
#pragma unroll
        for (int mi = 0; mi < 4; ++mi)
#pragma unroll
            for (int ni = 0; ni < 4; ++ni)
                acc[mi][ni] = __builtin_amdgcn_mfma_f32_16x16x32_bf16(af[mi], bfr[ni], acc[mi][ni], 0, 0, 0);
    }

    // epilogue: C/D layout col=lane&15, row=(lane>>4)*4+reg  [guide-verified]
    const int q = lane >> 4;
#pragma unroll
    for (int mi = 0; mi < 4; ++mi) {
#pragma unroll
        for (int v = 0; v < 4; ++v) {
            int row = brow + wr * 64 + mi * 16 + q * 4 + v;
            float ssi = ss[row];
            float rs = 0.f;
#pragma unroll
            for (int ni = 0; ni < 4; ++ni) {
                int col = bcol + wc * 64 + ni * 16 + r;
                float d2 = fmaxf(ssi + ss[col] - 2.0f * acc[mi][ni][v], 0.f);
                float o = (MODE == 0) ? __expf(-d2) : sqrtf(d2);
                out[(size_t)row * NN + col] = o;
                rs += o;
            }
            if (MODE == 1) {
#pragma unroll
                for (int o2 = 1; o2 < 16; o2 <<= 1) rs += __shfl_xor(rs, o2, 64);
                if (r == 0) atomicAdd(&rowsum[row], rs);
            }
        }
    }
}

// ---------------- top-10 per row of W_P with same-id override, tie: lower index first ----------------
__global__ void topk_kernel(const float* __restrict__ WP, const int* __restrict__ idx,
                            int* __restrict__ topk) {
    __shared__ unsigned long long sred[4];
    __shared__ unsigned long long sbest;
    int row = blockIdx.x, tid = threadIdx.x;
    int myid = idx[row];
    unsigned key[16];
#pragma unroll
    for (int a = 0; a < 16; ++a) {
        int j = tid + a * 256;
        float w = WP[(size_t)row * NN + j];
        if (idx[j] == myid) w = 1.0f;
        key[a] = __float_as_uint(w);  // w > 0 always -> monotonic as uint
    }
    int lane = tid & 63, wv = tid >> 6;
    for (int it = 0; it < 10; ++it) {
        unsigned long long best = 0;
#pragma unroll
        for (int a = 0; a < 16; ++a) {
            unsigned long long pk =
                ((unsigned long long)key[a] << 32) | (unsigned)(0xFFFFFFFFu - (unsigned)(tid + a * 256));
            if (pk > best) best = pk;
        }
#pragma unroll
        for (int o = 32; o > 0; o >>= 1) {
            unsigned long long t = __shfl_xor(best, o, 64);
            if (t > best) best = t;
        }
        if (lane == 0) sred[wv] = best;
        __syncthreads();
        if (tid == 0) {
            unsigned long long b = sred[0];
            for (int w2 = 1; w2 < 4; ++w2)
                if (sred[w2] > b) b = sred[w2];
            sbest = b;
        }
        __syncthreads();
        unsigned jstar = 0xFFFFFFFFu - (unsigned)(sbest & 0xFFFFFFFFu);
        if (tid == 0) topk[row * 10 + it] = (int)jstar;
        // static-indexed predicated clear (dynamic index would demote key[] to scratch)
        if ((jstar & 255u) == (unsigned)tid) {
            unsigned slot = jstar >> 8;
#pragma unroll
            for (int a = 0; a < 16; ++a)
                if ((unsigned)a == slot) key[a] = 0u;
        }
        __syncthreads();
    }
}

// ---------------- mutual-kNN adjacency: thread per (i,a); sentinel -1 slots ----------------
__global__ void mutual_kernel(const int* __restrict__ topk, int* __restrict__ nbr,
                              int* __restrict__ deg) {
    int gid = blockIdx.x * 256 + threadIdx.x;
    if (gid >= NN * 10) return;
    int i = gid / 10, a = gid - i * 10;
    int j = topk[i * 10 + a];
    bool mut = false;
#pragma unroll
    for (int b = 0; b < 10; ++b) mut = mut || (topk[j * 10 + b] == i);
    nbr[gid] = mut ? j : -1;
    if (mut) atomicAdd(&deg[i], 1);
}

// ---------------- W_C_tilda: thread per (m,a): |nbr(m) ∩ nbr(j)| / max(deg[m],1) ----------------
__global__ void tilda_kernel(const int* __restrict__ nbr, const int* __restrict__ deg,
                             float* __restrict__ tvals) {
    int gid = blockIdx.x * 256 + threadIdx.x;
    if (gid >= NN * 10) return;
    int m = gid / 10;
    int j = nbr[gid];
    if (j < 0) { tvals[gid] = 0.f; return; }
    int am[10], aj[10];
#pragma unroll
    for (int p = 0; p < 10; ++p) am[p] = nbr[m * 10 + p];
#pragma unroll
    for (int p = 0; p < 10; ++p) aj[p] = nbr[j * 10 + p];
    int cnt = 0;
#pragma unroll
    for (int p = 0; p < 10; ++p)
#pragma unroll
        for (int qq = 0; qq < 10; ++qq)
            cnt += (am[p] >= 0 && am[p] == aj[qq]) ? 1 : 0;
    int dm = deg[m];
    float dv = (float)(dm > 1 ? dm : 1);
    tvals[gid] = (float)cnt / dv;
}

// ---------------- W_C_hat: thread per (i,h); emit 10 slots verbatim (dups are additive) ----------------
__global__ void hat_kernel(const int* __restrict__ topk, const int* __restrict__ nbr,
                           const float* __restrict__ tvals, int* __restrict__ hcols,
                           float* __restrict__ hvals) {
    int gid = blockIdx.x * 256 + threadIdx.x;
    if (gid >= NN * 5) return;
    int i = gid / 5, h = gid - i * 5;
    int m = topk[i * 10 + h];
#pragma unroll
    for (int a = 0; a < 10; ++a) {
        int j = nbr[m * 10 + a];
        int slot = i * 50 + h * 10 + a;
        hcols[slot] = j;
        hvals[slot] = (j >= 0) ? tvals[m * 10 + a] * 0.2f : 0.f;
    }
}

// ---------------- fused: per-row inv-mean + logsumexp + RC dense (W_P part) + KL ----------------
__global__ void fused_dense_kernel(const float* __restrict__ Sf, const float* __restrict__ Sg,
                                   const float* __restrict__ WP, const float* __restrict__ rsf,
                                   const float* __restrict__ rsg, double* __restrict__ acc) {
    __shared__ float sbuf[4];
    int row = blockIdx.x, tid = threadIdx.x;
    float imf = (float)NN / rsf[row];
    float img = (float)NN / rsg[row];
    // load both rows into registers (16 + 16 VGPRs), pre-scaled
    float vf[16], vg[16];
#pragma unroll
    for (int a = 0; a < 16; ++a) {
        size_t o = (size_t)row * NN + tid + a * 256;
        vf[a] = Sf[o] * imf;
        vg[a] = Sg[o] * img;
    }
    float ef = 0.f, eg = 0.f;
#pragma unroll
    for (int a = 0; a < 16; ++a) {
        ef += __expf(-vf[a]);
        eg += __expf(-vg[a]);
    }
    float lf = logf(block_sum(ef, sbuf));
    float lg = logf(block_sum(eg, sbuf));
    float af = 0.f, ag = 0.f, akl = 0.f;
#pragma unroll
    for (int a = 0; a < 16; ++a) {
        int j = tid + a * 256;
        float wp = WP[(size_t)row * NN + j];
        float sf = vf[a], sg = vg[a];
        if (j != row) {
            float t = fmaxf(1.f - sf, 0.f);
            float pu = t * t;
            float gq = sf * sf - pu;
            af += pu + 0.5f * gq * wp;
            t = fmaxf(1.f - sg, 0.f);
            pu = t * t;
            gq = sg * sg - pu;
            ag += pu + 0.5f * gq * wp;
        }
        float lq = -sf - lf;
        float lp = -sg - lg;
        float pp = __expf(lp);
        akl += pp * (lp - lq);
    }
    float tf = block_sum(af, sbuf);
    float tg2 = block_sum(ag, sbuf);
    float tk = block_sum(akl, sbuf);
    if (tid == 0) {
        int bank = (row & 15) * 3;
        atomicAdd(&acc[bank + 0], (double)tf);
        atomicAdd(&acc[bank + 1], (double)tg2);
        atomicAdd(&acc[bank + 2], (double)tk);
    }
}

// ---------------- sparse W_C correction: wave per row, lanes 0..49 over hat slots ----------------
__global__ void sparse_kernel(const float* __restrict__ Sf, const float* __restrict__ Sg,
                              const int* __restrict__ hcols, const float* __restrict__ hvals,
                              const float* __restrict__ rsf, const float* __restrict__ rsg,
                              double* __restrict__ acc) {
    __shared__ float sbuf[4];
    int lane = threadIdx.x & 63, wv = threadIdx.x >> 6;
    int i = blockIdx.x * 4 + wv;
    float cf = 0.f, cg = 0.f;
    if (lane < 50) {
        int j = hcols[i * 50 + lane];
        if (j >= 0 && j != i) {
            float v = hvals[i * 50 + lane];
            float imfi = (float)NN / rsf[i];
            float imgi = (float)NN / rsg[i];
            float s1 = Sf[(size_t)i * NN + j] * imfi;
            float s2 = Sf[(size_t)j * NN + i] * ((float)NN / rsf[j]);
            float t1 = fmaxf(1.f - s1, 0.f), t2 = fmaxf(1.f - s2, 0.f);
            cf = v * ((s1 * s1 - t1 * t1) + (s2 * s2 - t2 * t2));
            s1 = Sg[(size_t)i * NN + j] * imgi;
            s2 = Sg[(size_t)j * NN + i] * ((float)NN / rsg[j]);
            t1 = fmaxf(1.f - s1, 0.f);
            t2 = fmaxf(1.f - s2, 0.f);
            cg = v * ((s1 * s1 - t1 * t1) + (s2 * s2 - t2 * t2));
        }
    }
    float tf = block_sum(cf, sbuf);
    float tg = block_sum(cg, sbuf);
    if (threadIdx.x == 0) {
        int bank = (blockIdx.x & 15) * 3;
        atomicAdd(&acc[bank + 0], (double)(0.25f * tf));
        atomicAdd(&acc[bank + 1], (double)(0.25f * tg));
    }
}

__global__ void finalize_kernel(const double* __restrict__ acc, float* __restrict__ out) {
    if (threadIdx.x == 0) {
        double a0 = 0.0, a1 = 0.0, a2 = 0.0;
        for (int b = 0; b < 16; ++b) {
            a0 += acc[b * 3 + 0];
            a1 += acc[b * 3 + 1];
            a2 += acc[b * 3 + 2];
        }
        double denom = (double)NN * (double)(NN - 1);
        double rcf = a0 / denom, rcg = a1 / denom;
        double rc = 0.5 * (rcf + rcg);
        double kl = a2 / (double)NN;
        out[0] = (float)rc;
        out[1] = (float)kl;
        out[2] = (float)(rc + kl);
    }
}

extern "C" void kernel_launch(void* const* d_in, const int* in_sizes, int n_in, void* d_out,
                              int out_size, void* d_ws, size_t ws_size, hipStream_t stream) {
    const float* s_f = (const float*)d_in[0];
    const float* s_g = (const float*)d_in[1];
    const float* t_g = (const float*)d_in[2];
    const int* idx = (const int*)d_in[3];
    float* out = (float*)d_out;

    char* base = (char*)d_ws;
    size_t off = 0;
    auto alloc = [&](size_t b) {
        char* p = base + off;
        off = (off + b + 255) & ~(size_t)255;
        return p;
    };
    double* acc = (double*)alloc(16 * 3 * 8);  // 16 banks x 3 doubles
    float* rowsum_f = (float*)alloc(NN * 4);
    float* rowsum_g = (float*)alloc(NN * 4);
    int* deg = (int*)alloc(NN * 4);
    size_t zero_bytes = off;  // acc + rowsums + deg zeroed each call
    u16* tb = (u16*)alloc((size_t)NN * 1024 * 2);
    u16* fb = (u16*)alloc((size_t)NN * 512 * 2);
    u16* gb = (u16*)alloc((size_t)NN * 512 * 2);
    float* ss_t = (float*)alloc(NN * 4);
    float* ss_f = (float*)alloc(NN * 4);
    float* ss_g = (float*)alloc(NN * 4);
    float* WP = (float*)alloc((size_t)NN * NN * 4);
    float* Sf = (float*)alloc((size_t)NN * NN * 4);
    float* Sg = (float*)alloc((size_t)NN * NN * 4);
    int* topk = (int*)alloc(NN * 10 * 4);
    int* nbr = (int*)alloc(NN * 10 * 4);
    float* tvals = (float*)alloc(NN * 10 * 4);
    int* hcols = (int*)alloc(NN * 50 * 4);
    float* hvals = (float*)alloc(NN * 50 * 4);

    hipMemsetAsync(d_ws, 0, zero_bytes, stream);

    normalize_kernel<1024><<<NN, 256, 0, stream>>>(t_g, tb, ss_t);
    normalize_kernel<512><<<NN, 256, 0, stream>>>(s_f, fb, ss_f);
    normalize_kernel<512><<<NN, 256, 0, stream>>>(s_g, gb, ss_g);

    gram_kernel<1024, 0><<<dim3(32, 32), 256, 0, stream>>>(tb, ss_t, WP, nullptr);
    gram_kernel<512, 1><<<dim3(32, 32), 256, 0, stream>>>(fb, ss_f, Sf, rowsum_f);
    gram_kernel<512, 1><<<dim3(32, 32), 256, 0, stream>>>(gb, ss_g, Sg, rowsum_g);

    topk_kernel<<<NN, 256, 0, stream>>>(WP, idx, topk);
    mutual_kernel<<<(NN * 10 + 255) / 256, 256, 0, stream>>>(topk, nbr, deg);
    tilda_kernel<<<(NN * 10 + 255) / 256, 256, 0, stream>>>(nbr, deg, tvals);
    hat_kernel<<<(NN * 5 + 255) / 256, 256, 0, stream>>>(topk, nbr, tvals, hcols, hvals);

    fused_dense_kernel<<<NN, 256, 0, stream>>>(Sf, Sg, WP, rowsum_f, rowsum_g, acc);
    sparse_kernel<<<NN / 4, 256, 0, stream>>>(Sf, Sg, hcols, hvals, rowsum_f, rowsum_g, acc);
    finalize_kernel<<<1, 64, 0, stream>>>(acc, out);
}

// Round 4
// 307.880 us; speedup vs baseline: 2.7337x; 1.0264x over previous
//
#include <hip/hip_runtime.h>
#include <hip/hip_bf16.h>

#define NN 4096
typedef unsigned short u16;
typedef __bf16 bf16x8 __attribute__((ext_vector_type(8)));
typedef float f32x4 __attribute__((ext_vector_type(4)));

typedef const __attribute__((address_space(1))) void* gptr_t;
typedef __attribute__((address_space(3))) void* lptr_t;

__device__ inline u16 bf16bits(float v) {
    __bf16 h = (__bf16)v;
    return __builtin_bit_cast(u16, h);
}
__device__ inline float bf16val(float v) {
    __bf16 h = (__bf16)v;
    return (float)h;
}

// ---------------- block reduction helper (256 threads / 4 waves) ----------------
__device__ inline float block_sum(float v, volatile float* sbuf) {
    int lane = threadIdx.x & 63, wv = threadIdx.x >> 6;
#pragma unroll
    for (int o = 32; o > 0; o >>= 1) v += __shfl_xor(v, o, 64);
    if (lane == 0) sbuf[wv] = v;
    __syncthreads();
    float r = sbuf[0] + sbuf[1] + sbuf[2] + sbuf[3];
    __syncthreads();
    return r;
}

// ---------------- normalize rows (float4), emit bf16 + sum-of-squares(bf16) ----------------
template <int D>
__global__ void normalize_kernel(const float* __restrict__ in, u16* __restrict__ outb,
                                 float* __restrict__ ssout) {
    __shared__ float sbuf[4];
    constexpr int NV = D / 4;  // 128 (D=512) or 256 (D=1024)
    int row = blockIdx.x, tid = threadIdx.x;
    const float4* x4 = (const float4*)(in + (size_t)row * D);
    float4 v = make_float4(0.f, 0.f, 0.f, 0.f);
    if (tid < NV) v = x4[tid];
    float s = v.x * v.x + v.y * v.y + v.z * v.z + v.w * v.w;
    float tot = block_sum(s, sbuf);
    float inv = 1.0f / fmaxf(sqrtf(tot), 1e-12f);
    float sb = 0.f;
    if (tid < NV) {
        float b0 = bf16val(v.x * inv), b1 = bf16val(v.y * inv);
        float b2 = bf16val(v.z * inv), b3 = bf16val(v.w * inv);
        ushort4 o;
        o.x = bf16bits(v.x * inv);
        o.y = bf16bits(v.y * inv);
        o.z = bf16bits(v.z * inv);
        o.w = bf16bits(v.w * inv);
        ((ushort4*)(outb + (size_t)row * D))[tid] = o;
        sb = b0 * b0 + b1 * b1 + b2 * b2 + b3 * b3;
    }
    float totb = block_sum(sb, sbuf);
    if (tid == 0) ssout[row] = totb;
}

// ---------------- Gram -> distance transform, 2-phase double-buffered staging ----------------
// MODE 0: W_P=exp(-d2); MODE 1: dist + rowsum
template <int K, int MODE>
__launch_bounds__(256)
__global__ void gram_kernel(const u16* __restrict__ X, const float* __restrict__ ss,
                            float* __restrict__ out, float* __restrict__ rowsum) {
    __shared__ __align__(16) u16 lA[2][128 * 32];
    __shared__ __align__(16) u16 lB[2][128 * 32];
    const int tid = threadIdx.x;
    const int wv = tid >> 6, lane = tid & 63;
    const int wr = wv >> 1, wc = wv & 1;
    const int brow = blockIdx.y * 128, bcol = blockIdx.x * 128;
    const int r = lane & 15, kc = lane >> 4;
    const int crow = lane >> 2;       // staging: row within 16-row chunk
    const int koff = (lane & 3) * 8;  // staging: element offset (16B granule)

    f32x4 acc[4][4];
#pragma unroll
    for (int mi = 0; mi < 4; ++mi)
#pragma unroll
        for (int ni = 0; ni < 4; ++ni) acc[mi][ni] = (f32x4){0.f, 0.f, 0.f, 0.f};

    // stage one 128x32 K-tile pair into buffer `buf` (8 chunks A + 8 chunks B over 4 waves)
    auto STAGE = [&](int buf, int k0) {
#pragma unroll
        for (int cc = 0; cc < 2; ++cc) {
            int c = wv * 2 + cc;  // c in [0,8)
            const u16* ga = X + (size_t)(brow + c * 16 + crow) * K + k0 + koff;
            const u16* gb = X + (size_t)(bcol + c * 16 + crow) * K + k0 + koff;
            __builtin_amdgcn_global_load_lds((gptr_t)ga, (lptr_t)&lA[buf][c * 512], 16, 0, 0);
            __builtin_amdgcn_global_load_lds((gptr_t)gb, (lptr_t)&lB[buf][c * 512], 16, 0, 0);
        }
    };

    constexpr int NT = K / 32;
    STAGE(0, 0);
    __syncthreads();  // drains vmcnt: buf0 ready
    for (int t = 0; t < NT; ++t) {
        int cur = t & 1;
        if (t + 1 < NT) STAGE(cur ^ 1, (t + 1) * 32);  // prefetch next tile (drained at loop barrier)

        bf16x8 af[4], bfr[4];
#pragma unroll
        for (int mi = 0; mi < 4; ++mi)
            af[mi] = *(const bf16x8*)&lA[cur][(wr * 64 + mi * 16 + r) * 32 + kc * 8];
#pragma unroll
        for (int ni = 0; ni < 4; ++ni)
            bfr[ni] = *(const bf16x8*)&lB[cur][(wc * 64 + ni * 16 + r) * 32 + kc * 8];
#pragma unroll
        for (int mi = 0; mi < 4; ++mi)
#pragma unroll
            for (int ni = 0; ni < 4; ++ni)
                acc[mi][ni] = __builtin_amdgcn_mfma_f32_16x16x32_bf16(af[mi], bfr[ni], acc[mi][ni], 0, 0, 0);

        __syncthreads();  // prefetch complete + all waves done reading buf[cur]
    }

    // epilogue: C/D layout col=lane&15, row=(lane>>4)*4+reg  [guide-verified]
    const int q = lane >> 4;
#pragma unroll
    for (int mi = 0; mi < 4; ++mi) {
#pragma unroll
        for (int v = 0; v < 4; ++v) {
            int row = brow + wr * 64 + mi * 16 + q * 4 + v;
            float ssi = ss[row];
            float rs = 0.f;
#pragma unroll
            for (int ni = 0; ni < 4; ++ni) {
                int col = bcol + wc * 64 + ni * 16 + r;
                float d2 = fmaxf(ssi + ss[col] - 2.0f * acc[mi][ni][v], 0.f);
                float o = (MODE == 0) ? __expf(-d2) : sqrtf(d2);
                out[(size_t)row * NN + col] = o;
                rs += o;
            }
            if (MODE == 1) {
#pragma unroll
                for (int o2 = 1; o2 < 16; o2 <<= 1) rs += __shfl_xor(rs, o2, 64);
                if (r == 0) atomicAdd(&rowsum[row], rs);
            }
        }
    }
}

// ---------------- top-10 per row of W_P (float4 loads), same-id override, tie: lower index ----------------
__global__ void topk_kernel(const float* __restrict__ WP, const int* __restrict__ idx,
                            int* __restrict__ topk) {
    __shared__ unsigned long long sred[4];
    __shared__ unsigned long long sbest;
    int row = blockIdx.x, tid = threadIdx.x;
    int myid = idx[row];
    const float4* WP4 = (const float4*)(WP + (size_t)row * NN);
    const int4* idx4 = (const int4*)idx;
    unsigned key[16];
#pragma unroll
    for (int a = 0; a < 4; ++a) {
        float4 w = WP4[a * 256 + tid];
        int4 id = idx4[a * 256 + tid];
        key[a * 4 + 0] = __float_as_uint(id.x == myid ? 1.0f : w.x);
        key[a * 4 + 1] = __float_as_uint(id.y == myid ? 1.0f : w.y);
        key[a * 4 + 2] = __float_as_uint(id.z == myid ? 1.0f : w.z);
        key[a * 4 + 3] = __float_as_uint(id.w == myid ? 1.0f : w.w);
    }
    int lane = tid & 63, wv = tid >> 6;
    for (int it = 0; it < 10; ++it) {
        unsigned long long best = 0;
#pragma unroll
        for (int a = 0; a < 4; ++a)
#pragma unroll
            for (int c = 0; c < 4; ++c) {
                unsigned j = (unsigned)((a * 256 + tid) * 4 + c);
                unsigned long long pk =
                    ((unsigned long long)key[a * 4 + c] << 32) | (0xFFFFFFFFu - j);
                if (pk > best) best = pk;
            }
#pragma unroll
        for (int o = 32; o > 0; o >>= 1) {
            unsigned long long t = __shfl_xor(best, o, 64);
            if (t > best) best = t;
        }
        if (lane == 0) sred[wv] = best;
        __syncthreads();
        if (tid == 0) {
            unsigned long long b = sred[0];
            for (int w2 = 1; w2 < 4; ++w2)
                if (sred[w2] > b) b = sred[w2];
            sbest = b;
        }
        __syncthreads();
        unsigned jstar = 0xFFFFFFFFu - (unsigned)(sbest & 0xFFFFFFFFu);
        if (tid == 0) topk[row * 10 + it] = (int)jstar;
        // owner thread clears the winning slot (static-indexed to stay in VGPRs)
        if (((jstar >> 2) & 255u) == (unsigned)tid) {
            unsigned slot = ((jstar >> 10) << 2) | (jstar & 3u);
#pragma unroll
            for (int a = 0; a < 16; ++a)
                if ((unsigned)a == slot) key[a] = 0u;
        }
        __syncthreads();
    }
}

// ---------------- mutual-kNN adjacency: thread per (i,a); sentinel -1 slots ----------------
__global__ void mutual_kernel(const int* __restrict__ topk, int* __restrict__ nbr,
                              int* __restrict__ deg) {
    int gid = blockIdx.x * 256 + threadIdx.x;
    if (gid >= NN * 10) return;
    int i = gid / 10, a = gid - i * 10;
    int j = topk[i * 10 + a];
    bool mut = false;
#pragma unroll
    for (int b = 0; b < 10; ++b) mut = mut || (topk[j * 10 + b] == i);
    nbr[gid] = mut ? j : -1;
    if (mut) atomicAdd(&deg[i], 1);
}

// ---------------- W_C_tilda: thread per (m,a): |nbr(m) ∩ nbr(j)| / max(deg[m],1) ----------------
__global__ void tilda_kernel(const int* __restrict__ nbr, const int* __restrict__ deg,
                             float* __restrict__ tvals) {
    int gid = blockIdx.x * 256 + threadIdx.x;
    if (gid >= NN * 10) return;
    int m = gid / 10;
    int j = nbr[gid];
    if (j < 0) { tvals[gid] = 0.f; return; }
    int am[10], aj[10];
#pragma unroll
    for (int p = 0; p < 10; ++p) am[p] = nbr[m * 10 + p];
#pragma unroll
    for (int p = 0; p < 10; ++p) aj[p] = nbr[j * 10 + p];
    int cnt = 0;
#pragma unroll
    for (int p = 0; p < 10; ++p)
#pragma unroll
        for (int qq = 0; qq < 10; ++qq)
            cnt += (am[p] >= 0 && am[p] == aj[qq]) ? 1 : 0;
    int dm = deg[m];
    float dv = (float)(dm > 1 ? dm : 1);
    tvals[gid] = (float)cnt / dv;
}

// ---------------- W_C_hat: thread per (i,h); emit 10 slots verbatim (dups are additive) ----------------
__global__ void hat_kernel(const int* __restrict__ topk, const int* __restrict__ nbr,
                           const float* __restrict__ tvals, int* __restrict__ hcols,
                           float* __restrict__ hvals) {
    int gid = blockIdx.x * 256 + threadIdx.x;
    if (gid >= NN * 5) return;
    int i = gid / 5, h = gid - i * 5;
    int m = topk[i * 10 + h];
#pragma unroll
    for (int a = 0; a < 10; ++a) {
        int j = nbr[m * 10 + a];
        int slot = i * 50 + h * 10 + a;
        hcols[slot] = j;
        hvals[slot] = (j >= 0) ? tvals[m * 10 + a] * 0.2f : 0.f;
    }
}

// ---------------- fused: per-row inv-mean + logsumexp + RC dense (W_P part) + KL ----------------
__global__ void fused_dense_kernel(const float* __restrict__ Sf, const float* __restrict__ Sg,
                                   const float* __restrict__ WP, const float* __restrict__ rsf,
                                   const float* __restrict__ rsg, double* __restrict__ acc) {
    __shared__ float sbuf[4];
    int row = blockIdx.x, tid = threadIdx.x;
    float imf = (float)NN / rsf[row];
    float img = (float)NN / rsg[row];
    const float4* Sf4 = (const float4*)(Sf + (size_t)row * NN);
    const float4* Sg4 = (const float4*)(Sg + (size_t)row * NN);
    const float4* WP4 = (const float4*)(WP + (size_t)row * NN);
    float4 f4[4], g4[4];
#pragma unroll
    for (int a = 0; a < 4; ++a) {
        f4[a] = Sf4[a * 256 + tid];
        g4[a] = Sg4[a * 256 + tid];
    }
    float vf[16], vg[16];
#pragma unroll
    for (int a = 0; a < 4; ++a) {
        vf[a * 4 + 0] = f4[a].x * imf; vf[a * 4 + 1] = f4[a].y * imf;
        vf[a * 4 + 2] = f4[a].z * imf; vf[a * 4 + 3] = f4[a].w * imf;
        vg[a * 4 + 0] = g4[a].x * img; vg[a * 4 + 1] = g4[a].y * img;
        vg[a * 4 + 2] = g4[a].z * img; vg[a * 4 + 3] = g4[a].w * img;
    }
    float ef = 0.f, eg = 0.f;
#pragma unroll
    for (int a = 0; a < 16; ++a) {
        ef += __expf(-vf[a]);
        eg += __expf(-vg[a]);
    }
    float lf = logf(block_sum(ef, sbuf));
    float lg = logf(block_sum(eg, sbuf));
    float4 w4[4];
#pragma unroll
    for (int a = 0; a < 4; ++a) w4[a] = WP4[a * 256 + tid];
    float af = 0.f, ag = 0.f, akl = 0.f;
#pragma unroll
    for (int a = 0; a < 4; ++a) {
#pragma unroll
        for (int c = 0; c < 4; ++c) {
            int j = (a * 256 + tid) * 4 + c;
            float wp = (c == 0) ? w4[a].x : (c == 1) ? w4[a].y : (c == 2) ? w4[a].z : w4[a].w;
            float sf = vf[a * 4 + c], sg = vg[a * 4 + c];
            if (j != row) {
                float t = fmaxf(1.f - sf, 0.f);
                float pu = t * t;
                float gq = sf * sf - pu;
                af += pu + 0.5f * gq * wp;
                t = fmaxf(1.f - sg, 0.f);
                pu = t * t;
                gq = sg * sg - pu;
                ag += pu + 0.5f * gq * wp;
            }
            float lq = -sf - lf;
            float lp = -sg - lg;
            float pp = __expf(lp);
            akl += pp * (lp - lq);
        }
    }
    float tf = block_sum(af, sbuf);
    float tg2 = block_sum(ag, sbuf);
    float tk = block_sum(akl, sbuf);
    if (tid == 0) {
        int bank = (row & 15) * 3;
        atomicAdd(&acc[bank + 0], (double)tf);
        atomicAdd(&acc[bank + 1], (double)tg2);
        atomicAdd(&acc[bank + 2], (double)tk);
    }
}

// ---------------- sparse W_C correction: wave per row, lanes 0..49 over hat slots ----------------
__global__ void sparse_kernel(const float* __restrict__ Sf, const float* __restrict__ Sg,
                              const int* __restrict__ hcols, const float* __restrict__ hvals,
                              const float* __restrict__ rsf, const float* __restrict__ rsg,
                              double* __restrict__ acc) {
    __shared__ float sbuf[4];
    int lane = threadIdx.x & 63, wv = threadIdx.x >> 6;
    int i = blockIdx.x * 4 + wv;
    float cf = 0.f, cg = 0.f;
    if (lane < 50) {
        int j = hcols[i * 50 + lane];
        if (j >= 0 && j != i) {
            float v = hvals[i * 50 + lane];
            float imfi = (float)NN / rsf[i];
            float imgi = (float)NN / rsg[i];
            float s1 = Sf[(size_t)i * NN + j] * imfi;
            float s2 = Sf[(size_t)j * NN + i] * ((float)NN / rsf[j]);
            float t1 = fmaxf(1.f - s1, 0.f), t2 = fmaxf(1.f - s2, 0.f);
            cf = v * ((s1 * s1 - t1 * t1) + (s2 * s2 - t2 * t2));
            s1 = Sg[(size_t)i * NN + j] * imgi;
            s2 = Sg[(size_t)j * NN + i] * ((float)NN / rsg[j]);
            t1 = fmaxf(1.f - s1, 0.f);
            t2 = fmaxf(1.f - s2, 0.f);
            cg = v * ((s1 * s1 - t1 * t1) + (s2 * s2 - t2 * t2));
        }
    }
    float tf = block_sum(cf, sbuf);
    float tg = block_sum(cg, sbuf);
    if (threadIdx.x == 0) {
        int bank = (blockIdx.x & 15) * 3;
        atomicAdd(&acc[bank + 0], (double)(0.25f * tf));
        atomicAdd(&acc[bank + 1], (double)(0.25f * tg));
    }
}

__global__ void finalize_kernel(const double* __restrict__ acc, float* __restrict__ out) {
    if (threadIdx.x == 0) {
        double a0 = 0.0, a1 = 0.0, a2 = 0.0;
        for (int b = 0; b < 16; ++b) {
            a0 += acc[b * 3 + 0];
            a1 += acc[b * 3 + 1];
            a2 += acc[b * 3 + 2];
        }
        double denom = (double)NN * (double)(NN - 1);
        double rcf = a0 / denom, rcg = a1 / denom;
        double rc = 0.5 * (rcf + rcg);
        double kl = a2 / (double)NN;
        out[0] = (float)rc;
        out[1] = (float)kl;
        out[2] = (float)(rc + kl);
    }
}

extern "C" void kernel_launch(void* const* d_in, const int* in_sizes, int n_in, void* d_out,
                              int out_size, void* d_ws, size_t ws_size, hipStream_t stream) {
    const float* s_f = (const float*)d_in[0];
    const float* s_g = (const float*)d_in[1];
    const float* t_g = (const float*)d_in[2];
    const int* idx = (const int*)d_in[3];
    float* out = (float*)d_out;

    char* base = (char*)d_ws;
    size_t off = 0;
    auto alloc = [&](size_t b) {
        char* p = base + off;
        off = (off + b + 255) & ~(size_t)255;
        return p;
    };
    double* acc = (double*)alloc(16 * 3 * 8);  // 16 banks x 3 doubles
    float* rowsum_f = (float*)alloc(NN * 4);
    float* rowsum_g = (float*)alloc(NN * 4);
    int* deg = (int*)alloc(NN * 4);
    size_t zero_bytes = off;  // acc + rowsums + deg zeroed each call
    u16* tb = (u16*)alloc((size_t)NN * 1024 * 2);
    u16* fb = (u16*)alloc((size_t)NN * 512 * 2);
    u16* gb = (u16*)alloc((size_t)NN * 512 * 2);
    float* ss_t = (float*)alloc(NN * 4);
    float* ss_f = (float*)alloc(NN * 4);
    float* ss_g = (float*)alloc(NN * 4);
    float* WP = (float*)alloc((size_t)NN * NN * 4);
    float* Sf = (float*)alloc((size_t)NN * NN * 4);
    float* Sg = (float*)alloc((size_t)NN * NN * 4);
    int* topk = (int*)alloc(NN * 10 * 4);
    int* nbr = (int*)alloc(NN * 10 * 4);
    float* tvals = (float*)alloc(NN * 10 * 4);
    int* hcols = (int*)alloc(NN * 50 * 4);
    float* hvals = (float*)alloc(NN * 50 * 4);

    hipMemsetAsync(d_ws, 0, zero_bytes, stream);

    normalize_kernel<1024><<<NN, 256, 0, stream>>>(t_g, tb, ss_t);
    normalize_kernel<512><<<NN, 256, 0, stream>>>(s_f, fb, ss_f);
    normalize_kernel<512><<<NN, 256, 0, stream>>>(s_g, gb, ss_g);

    gram_kernel<1024, 0><<<dim3(32, 32), 256, 0, stream>>>(tb, ss_t, WP, nullptr);
    gram_kernel<512, 1><<<dim3(32, 32), 256, 0, stream>>>(fb, ss_f, Sf, rowsum_f);
    gram_kernel<512, 1><<<dim3(32, 32), 256, 0, stream>>>(gb, ss_g, Sg, rowsum_g);

    topk_kernel<<<NN, 256, 0, stream>>>(WP, idx, topk);
    mutual_kernel<<<(NN * 10 + 255) / 256, 256, 0, stream>>>(topk, nbr, deg);
    tilda_kernel<<<(NN * 10 + 255) / 256, 256, 0, stream>>>(nbr, deg, tvals);
    hat_kernel<<<(NN * 5 + 255) / 256, 256, 0, stream>>>(topk, nbr, tvals, hcols, hvals);

    fused_dense_kernel<<<NN, 256, 0, stream>>>(Sf, Sg, WP, rowsum_f, rowsum_g, acc);
    sparse_kernel<<<NN / 4, 256, 0, stream>>>(Sf, Sg, hcols, hvals, rowsum_f, rowsum_g, acc);
    finalize_kernel<<<1, 64, 0, stream>>>(acc, out);
}

// Round 5
// 240.575 us; speedup vs baseline: 3.4985x; 1.2798x over previous
//
#include <hip/hip_runtime.h>
#include <hip/hip_bf16.h>

#define NN 4096
typedef unsigned short u16;
typedef __bf16 bf16x8 __attribute__((ext_vector_type(8)));
typedef float f32x4 __attribute__((ext_vector_type(4)));
typedef u16 u16x8 __attribute__((ext_vector_type(8)));

typedef const __attribute__((address_space(1))) void* gptr_t;
typedef __attribute__((address_space(3))) void* lptr_t;

__device__ inline u16 bf16bits(float v) {
    __bf16 h = (__bf16)v;
    return __builtin_bit_cast(u16, h);
}
__device__ inline float bf16val(float v) {
    __bf16 h = (__bf16)v;
    return (float)h;
}
__device__ inline float b2f(u16 b) { return __uint_as_float(((unsigned)b) << 16); }

// ---------------- block reduction helper (256 threads / 4 waves) ----------------
__device__ inline float block_sum(float v, volatile float* sbuf) {
    int lane = threadIdx.x & 63, wv = threadIdx.x >> 6;
#pragma unroll
    for (int o = 32; o > 0; o >>= 1) v += __shfl_xor(v, o, 64);
    if (lane == 0) sbuf[wv] = v;
    __syncthreads();
    float r = sbuf[0] + sbuf[1] + sbuf[2] + sbuf[3];
    __syncthreads();
    return r;
}

// ---------------- normalize rows (float4), emit bf16 + sum-of-squares(bf16) ----------------
template <int D>
__global__ void normalize_kernel(const float* __restrict__ in, u16* __restrict__ outb,
                                 float* __restrict__ ssout) {
    __shared__ float sbuf[4];
    constexpr int NV = D / 4;
    int row = blockIdx.x, tid = threadIdx.x;
    const float4* x4 = (const float4*)(in + (size_t)row * D);
    float4 v = make_float4(0.f, 0.f, 0.f, 0.f);
    if (tid < NV) v = x4[tid];
    float s = v.x * v.x + v.y * v.y + v.z * v.z + v.w * v.w;
    float tot = block_sum(s, sbuf);
    float inv = 1.0f / fmaxf(sqrtf(tot), 1e-12f);
    float sb = 0.f;
    if (tid < NV) {
        float b0 = bf16val(v.x * inv), b1 = bf16val(v.y * inv);
        float b2 = bf16val(v.z * inv), b3 = bf16val(v.w * inv);
        ushort4 o;
        o.x = bf16bits(v.x * inv);
        o.y = bf16bits(v.y * inv);
        o.z = bf16bits(v.z * inv);
        o.w = bf16bits(v.w * inv);
        ((ushort4*)(outb + (size_t)row * D))[tid] = o;
        sb = b0 * b0 + b1 * b1 + b2 * b2 + b3 * b3;
    }
    float totb = block_sum(sb, sbuf);
    if (tid == 0) ssout[row] = totb;
}

// ---------------- merged symmetric Gram kernel ----------------
// 1584 blocks: [0,528) -> t (K=1024, W_P=exp(-d2)); [528,1056) -> f; [1056,1584) -> g
// (K=512, S=sqrt(d2) + rowsum). Upper-triangle (by<=bx) blocks only; each block
// writes its 128x128 bf16 tile and (if off-diagonal) the transposed tile.
#define TS 132  // LDS tile row stride in u16 (264B: 8B-aligned, conflict-free b64 reads)
__launch_bounds__(256)
__global__ void gram_merged(const u16* __restrict__ tb, const u16* __restrict__ fb,
                            const u16* __restrict__ gb, const float* __restrict__ ss_t,
                            const float* __restrict__ ss_f, const float* __restrict__ ss_g,
                            u16* __restrict__ WP, u16* __restrict__ Sf, u16* __restrict__ Sg,
                            float* __restrict__ rsf, float* __restrict__ rsg) {
    __shared__ __align__(16) u16 smem[128 * TS];  // 33792 B; staging uses first 32768 B

    int bid = blockIdx.x;
    int which = (bid < 528) ? 0 : (bid < 1056 ? 1 : 2);
    int lb = bid - (which == 0 ? 0 : (which == 1 ? 528 : 1056));
    // triangular decode: (by, bx) with bx >= by, 32x32 tile grid
    int by = 0, rem = lb;
    while (rem >= 32 - by) { rem -= 32 - by; ++by; }
    int bx = by + rem;

    const u16* X = (which == 0) ? tb : (which == 1 ? fb : gb);
    const float* ss = (which == 0) ? ss_t : (which == 1 ? ss_f : ss_g);
    u16* outp = (which == 0) ? WP : (which == 1 ? Sf : Sg);
    float* rowsum = (which == 0) ? nullptr : (which == 1 ? rsf : rsg);
    const int K = (which == 0) ? 1024 : 512;
    const bool mode1 = (which != 0);

    const int tid = threadIdx.x;
    const int wv = tid >> 6, lane = tid & 63;
    const int wr = wv >> 1, wc = wv & 1;
    const int brow = by * 128, bcol = bx * 128;
    const int r = lane & 15, kc = lane >> 4;
    const int crow = lane >> 2;       // staging: row within 16-row chunk
    const int koff = (lane & 3) * 8;  // staging: element offset (16B granule)

    f32x4 acc[4][4];
#pragma unroll
    for (int mi = 0; mi < 4; ++mi)
#pragma unroll
        for (int ni = 0; ni < 4; ++ni) acc[mi][ni] = (f32x4){0.f, 0.f, 0.f, 0.f};

    // staging layout: A buf b at smem[b*4096 .. +4096), B buf b at smem[8192 + b*4096 ..)
    auto STAGE = [&](int buf, int k0) {
#pragma unroll
        for (int cc = 0; cc < 2; ++cc) {
            int c = wv * 2 + cc;  // c in [0,8)
            const u16* ga = X + (size_t)(brow + c * 16 + crow) * K + k0 + koff;
            const u16* gbp = X + (size_t)(bcol + c * 16 + crow) * K + k0 + koff;
            __builtin_amdgcn_global_load_lds((gptr_t)ga, (lptr_t)&smem[buf * 4096 + c * 512], 16, 0, 0);
            __builtin_amdgcn_global_load_lds((gptr_t)gbp, (lptr_t)&smem[8192 + buf * 4096 + c * 512], 16, 0, 0);
        }
    };

    const int NT = K / 32;
    STAGE(0, 0);
    __syncthreads();  // drains vmcnt: buf0 ready
    for (int t = 0; t < NT; ++t) {
        int cur = t & 1;
        if (t + 1 < NT) STAGE(cur ^ 1, (t + 1) * 32);

        bf16x8 af[4], bfr[4];
#pragma unroll
        for (int mi = 0; mi < 4; ++mi)
            af[mi] = *(const bf16x8*)&smem[cur * 4096 + (wr * 64 + mi * 16 + r) * 32 + kc * 8];
#pragma unroll
        for (int ni = 0; ni < 4; ++ni)
            bfr[ni] = *(const bf16x8*)&smem[8192 + cur * 4096 + (wc * 64 + ni * 16 + r) * 32 + kc * 8];
#pragma unroll
        for (int mi = 0; mi < 4; ++mi)
#pragma unroll
            for (int ni = 0; ni < 4; ++ni)
                acc[mi][ni] = __builtin_amdgcn_mfma_f32_16x16x32_bf16(af[mi], bfr[ni], acc[mi][ni], 0, 0, 0);

        __syncthreads();  // prefetch complete + all waves done reading buf[cur]
    }

    // epilogue: transform acc -> bf16 LDS tile (C/D layout col=lane&15, row=(lane>>4)*4+reg)
    u16* tile = smem;
    const int q = lane >> 4;
#pragma unroll
    for (int mi = 0; mi < 4; ++mi) {
#pragma unroll
        for (int v = 0; v < 4; ++v) {
            int rl = wr * 64 + mi * 16 + q * 4 + v;
            float ssi = ss[brow + rl];
#pragma unroll
            for (int ni = 0; ni < 4; ++ni) {
                int cl = wc * 64 + ni * 16 + r;
                float d2 = fmaxf(ssi + ss[bcol + cl] - 2.0f * acc[mi][ni][v], 0.f);
                float o = mode1 ? sqrtf(d2) : __expf(-d2);
                tile[rl * TS + cl] = bf16bits(o);
            }
        }
    }
    __syncthreads();

    // pass 1: coalesced writeout of tile rows + row sums
    {
        int rl = tid >> 1, hf = tid & 1;
        const u16* srow = &tile[rl * TS + hf * 64];
        u16* drow = outp + (size_t)(brow + rl) * NN + bcol + hf * 64;
        float rs = 0.f;
#pragma unroll
        for (int i = 0; i < 8; ++i) {
            ushort4 aa = *(const ushort4*)(srow + i * 8);
            ushort4 bb = *(const ushort4*)(srow + i * 8 + 4);
            u16x8 pk = {aa.x, aa.y, aa.z, aa.w, bb.x, bb.y, bb.z, bb.w};
            *(u16x8*)(drow + i * 8) = pk;
            if (mode1)
                rs += b2f(aa.x) + b2f(aa.y) + b2f(aa.z) + b2f(aa.w) +
                      b2f(bb.x) + b2f(bb.y) + b2f(bb.z) + b2f(bb.w);
        }
        if (mode1) {
            rs += __shfl_xor(rs, 1, 64);
            if (hf == 0) atomicAdd(&rowsum[brow + rl], rs);
        }
    }

    // pass 2 (off-diagonal blocks): transposed writeout + col sums
    if (bx != by) {
        int c = tid >> 1, hf = tid & 1;
        u16* drow = outp + (size_t)(bcol + c) * NN + brow + hf * 64;
        float rs = 0.f;
#pragma unroll
        for (int s = 0; s < 8; ++s) {
            u16 g[8];
#pragma unroll
            for (int u = 0; u < 8; ++u) g[u] = tile[(hf * 64 + s * 8 + u) * TS + c];
            u16x8 pk = {g[0], g[1], g[2], g[3], g[4], g[5], g[6], g[7]};
            *(u16x8*)(drow + s * 8) = pk;
            if (mode1)
#pragma unroll
                for (int u = 0; u < 8; ++u) rs += b2f(g[u]);
        }
        if (mode1) {
            rs += __shfl_xor(rs, 1, 64);
            if (hf == 0) atomicAdd(&rowsum[bcol + c], rs);
        }
    }
}

// ---------------- top-10 per row of W_P (bf16, ushort8 loads), same-id override ----------------
__global__ void topk_kernel(const u16* __restrict__ WP, const int* __restrict__ idx,
                            int* __restrict__ topk) {
    __shared__ unsigned long long sred[4];
    __shared__ unsigned long long sbest;
    int row = blockIdx.x, tid = threadIdx.x;
    int myid = idx[row];
    const u16x8* W8 = (const u16x8*)(WP + (size_t)row * NN);
    const int4* idx4 = (const int4*)idx;
    unsigned key[16];
#pragma unroll
    for (int a = 0; a < 2; ++a) {
        u16x8 w = W8[a * 256 + tid];
        int4 iA = idx4[a * 512 + tid * 2];
        int4 iB = idx4[a * 512 + tid * 2 + 1];
        int ids[8] = {iA.x, iA.y, iA.z, iA.w, iB.x, iB.y, iB.z, iB.w};
#pragma unroll
        for (int c = 0; c < 8; ++c)
            key[a * 8 + c] = (ids[c] == myid) ? 0x3F800000u : (((unsigned)w[c]) << 16);
    }
    int lane = tid & 63, wv = tid >> 6;
    for (int it = 0; it < 10; ++it) {
        unsigned long long best = 0;
#pragma unroll
        for (int a = 0; a < 2; ++a)
#pragma unroll
            for (int c = 0; c < 8; ++c) {
                unsigned j = (unsigned)(a * 2048 + tid * 8 + c);
                unsigned long long pk =
                    ((unsigned long long)key[a * 8 + c] << 32) | (0xFFFFFFFFu - j);
                if (pk > best) best = pk;
            }
#pragma unroll
        for (int o = 32; o > 0; o >>= 1) {
            unsigned long long t = __shfl_xor(best, o, 64);
            if (t > best) best = t;
        }
        if (lane == 0) sred[wv] = best;
        __syncthreads();
        if (tid == 0) {
            unsigned long long b = sred[0];
            for (int w2 = 1; w2 < 4; ++w2)
                if (sred[w2] > b) b = sred[w2];
            sbest = b;
        }
        __syncthreads();
        unsigned jstar = 0xFFFFFFFFu - (unsigned)(sbest & 0xFFFFFFFFu);
        if (tid == 0) topk[row * 10 + it] = (int)jstar;
        if (((jstar >> 3) & 255u) == (unsigned)tid) {
            unsigned slot = ((jstar >> 11) << 3) | (jstar & 7u);
#pragma unroll
            for (int a = 0; a < 16; ++a)
                if ((unsigned)a == slot) key[a] = 0u;
        }
        __syncthreads();
    }
}

// ---------------- mutual-kNN adjacency: thread per (i,a); sentinel -1 slots ----------------
__global__ void mutual_kernel(const int* __restrict__ topk, int* __restrict__ nbr,
                              int* __restrict__ deg) {
    int gid = blockIdx.x * 256 + threadIdx.x;
    if (gid >= NN * 10) return;
    int i = gid / 10, a = gid - i * 10;
    int j = topk[i * 10 + a];
    bool mut = false;
#pragma unroll
    for (int b = 0; b < 10; ++b) mut = mut || (topk[j * 10 + b] == i);
    nbr[gid] = mut ? j : -1;
    if (mut) atomicAdd(&deg[i], 1);
}

// ---------------- W_C_tilda: thread per (m,a) ----------------
__global__ void tilda_kernel(const int* __restrict__ nbr, const int* __restrict__ deg,
                             float* __restrict__ tvals) {
    int gid = blockIdx.x * 256 + threadIdx.x;
    if (gid >= NN * 10) return;
    int m = gid / 10;
    int j = nbr[gid];
    if (j < 0) { tvals[gid] = 0.f; return; }
    int am[10], aj[10];
#pragma unroll
    for (int p = 0; p < 10; ++p) am[p] = nbr[m * 10 + p];
#pragma unroll
    for (int p = 0; p < 10; ++p) aj[p] = nbr[j * 10 + p];
    int cnt = 0;
#pragma unroll
    for (int p = 0; p < 10; ++p)
#pragma unroll
        for (int qq = 0; qq < 10; ++qq)
            cnt += (am[p] >= 0 && am[p] == aj[qq]) ? 1 : 0;
    int dm = deg[m];
    float dv = (float)(dm > 1 ? dm : 1);
    tvals[gid] = (float)cnt / dv;
}

// ---------------- W_C_hat: thread per (i,h); emit 10 slots verbatim ----------------
__global__ void hat_kernel(const int* __restrict__ topk, const int* __restrict__ nbr,
                           const float* __restrict__ tvals, int* __restrict__ hcols,
                           float* __restrict__ hvals) {
    int gid = blockIdx.x * 256 + threadIdx.x;
    if (gid >= NN * 5) return;
    int i = gid / 5, h = gid - i * 5;
    int m = topk[i * 10 + h];
#pragma unroll
    for (int a = 0; a < 10; ++a) {
        int j = nbr[m * 10 + a];
        int slot = i * 50 + h * 10 + a;
        hcols[slot] = j;
        hvals[slot] = (j >= 0) ? tvals[m * 10 + a] * 0.2f : 0.f;
    }
}

// ---------------- fused: per-row inv-mean + logsumexp + RC dense (W_P part) + KL ----------------
__global__ void fused_dense_kernel(const u16* __restrict__ Sf, const u16* __restrict__ Sg,
                                   const u16* __restrict__ WP, const float* __restrict__ rsf,
                                   const float* __restrict__ rsg, double* __restrict__ acc) {
    __shared__ float sbuf[4];
    int row = blockIdx.x, tid = threadIdx.x;
    float imf = (float)NN / rsf[row];
    float img = (float)NN / rsg[row];
    const u16x8* f8 = (const u16x8*)(Sf + (size_t)row * NN);
    const u16x8* g8 = (const u16x8*)(Sg + (size_t)row * NN);
    const u16x8* w8 = (const u16x8*)(WP + (size_t)row * NN);
    u16x8 fr[2], gr[2];
#pragma unroll
    for (int a = 0; a < 2; ++a) {
        fr[a] = f8[a * 256 + tid];
        gr[a] = g8[a * 256 + tid];
    }
    float vf[16], vg[16];
#pragma unroll
    for (int a = 0; a < 2; ++a)
#pragma unroll
        for (int c = 0; c < 8; ++c) {
            vf[a * 8 + c] = b2f(fr[a][c]) * imf;
            vg[a * 8 + c] = b2f(gr[a][c]) * img;
        }
    float ef = 0.f, eg = 0.f;
#pragma unroll
    for (int a = 0; a < 16; ++a) {
        ef += __expf(-vf[a]);
        eg += __expf(-vg[a]);
    }
    float lf = logf(block_sum(ef, sbuf));
    float lg = logf(block_sum(eg, sbuf));
    u16x8 wr2[2];
#pragma unroll
    for (int a = 0; a < 2; ++a) wr2[a] = w8[a * 256 + tid];
    float af = 0.f, ag = 0.f, akl = 0.f;
#pragma unroll
    for (int a = 0; a < 2; ++a) {
#pragma unroll
        for (int c = 0; c < 8; ++c) {
            int j = a * 2048 + tid * 8 + c;
            float wp = b2f(wr2[a][c]);
            float sf = vf[a * 8 + c], sg = vg[a * 8 + c];
            if (j != row) {
                float t = fmaxf(1.f - sf, 0.f);
                float pu = t * t;
                float gq = sf * sf - pu;
                af += pu + 0.5f * gq * wp;
                t = fmaxf(1.f - sg, 0.f);
                pu = t * t;
                gq = sg * sg - pu;
                ag += pu + 0.5f * gq * wp;
            }
            float lq = -sf - lf;
            float lp = -sg - lg;
            float pp = __expf(lp);
            akl += pp * (lp - lq);
        }
    }
    float tf = block_sum(af, sbuf);
    float tg2 = block_sum(ag, sbuf);
    float tk = block_sum(akl, sbuf);
    if (tid == 0) {
        int bank = (row & 15) * 3;
        atomicAdd(&acc[bank + 0], (double)tf);
        atomicAdd(&acc[bank + 1], (double)tg2);
        atomicAdd(&acc[bank + 2], (double)tk);
    }
}

// ---------------- sparse W_C correction: wave per row, lanes 0..49 over hat slots ----------------
__global__ void sparse_kernel(const u16* __restrict__ Sf, const u16* __restrict__ Sg,
                              const int* __restrict__ hcols, const float* __restrict__ hvals,
                              const float* __restrict__ rsf, const float* __restrict__ rsg,
                              double* __restrict__ acc) {
    __shared__ float sbuf[4];
    int lane = threadIdx.x & 63, wv = threadIdx.x >> 6;
    int i = blockIdx.x * 4 + wv;
    float cf = 0.f, cg = 0.f;
    if (lane < 50) {
        int j = hcols[i * 50 + lane];
        if (j >= 0 && j != i) {
            float v = hvals[i * 50 + lane];
            float imfi = (float)NN / rsf[i];
            float imgi = (float)NN / rsg[i];
            float s1 = b2f(Sf[(size_t)i * NN + j]) * imfi;
            float s2 = b2f(Sf[(size_t)j * NN + i]) * ((float)NN / rsf[j]);
            float t1 = fmaxf(1.f - s1, 0.f), t2 = fmaxf(1.f - s2, 0.f);
            cf = v * ((s1 * s1 - t1 * t1) + (s2 * s2 - t2 * t2));
            s1 = b2f(Sg[(size_t)i * NN + j]) * imgi;
            s2 = b2f(Sg[(size_t)j * NN + i]) * ((float)NN / rsg[j]);
            t1 = fmaxf(1.f - s1, 0.f);
            t2 = fmaxf(1.f - s2, 0.f);
            cg = v * ((s1 * s1 - t1 * t1) + (s2 * s2 - t2 * t2));
        }
    }
    float tf = block_sum(cf, sbuf);
    float tg = block_sum(cg, sbuf);
    if (threadIdx.x == 0) {
        int bank = (blockIdx.x & 15) * 3;
        atomicAdd(&acc[bank + 0], (double)(0.25f * tf));
        atomicAdd(&acc[bank + 1], (double)(0.25f * tg));
    }
}

__global__ void finalize_kernel(const double* __restrict__ acc, float* __restrict__ out) {
    if (threadIdx.x == 0) {
        double a0 = 0.0, a1 = 0.0, a2 = 0.0;
        for (int b = 0; b < 16; ++b) {
            a0 += acc[b * 3 + 0];
            a1 += acc[b * 3 + 1];
            a2 += acc[b * 3 + 2];
        }
        double denom = (double)NN * (double)(NN - 1);
        double rcf = a0 / denom, rcg = a1 / denom;
        double rc = 0.5 * (rcf + rcg);
        double kl = a2 / (double)NN;
        out[0] = (float)rc;
        out[1] = (float)kl;
        out[2] = (float)(rc + kl);
    }
}

extern "C" void kernel_launch(void* const* d_in, const int* in_sizes, int n_in, void* d_out,
                              int out_size, void* d_ws, size_t ws_size, hipStream_t stream) {
    const float* s_f = (const float*)d_in[0];
    const float* s_g = (const float*)d_in[1];
    const float* t_g = (const float*)d_in[2];
    const int* idx = (const int*)d_in[3];
    float* out = (float*)d_out;

    char* base = (char*)d_ws;
    size_t off = 0;
    auto alloc = [&](size_t b) {
        char* p = base + off;
        off = (off + b + 255) & ~(size_t)255;
        return p;
    };
    double* acc = (double*)alloc(16 * 3 * 8);  // 16 banks x 3 doubles
    float* rowsum_f = (float*)alloc(NN * 4);
    float* rowsum_g = (float*)alloc(NN * 4);
    int* deg = (int*)alloc(NN * 4);
    size_t zero_bytes = off;  // acc + rowsums + deg zeroed each call
    u16* tb = (u16*)alloc((size_t)NN * 1024 * 2);
    u16* fb = (u16*)alloc((size_t)NN * 512 * 2);
    u16* gb = (u16*)alloc((size_t)NN * 512 * 2);
    float* ss_t = (float*)alloc(NN * 4);
    float* ss_f = (float*)alloc(NN * 4);
    float* ss_g = (float*)alloc(NN * 4);
    u16* WP = (u16*)alloc((size_t)NN * NN * 2);
    u16* Sf = (u16*)alloc((size_t)NN * NN * 2);
    u16* Sg = (u16*)alloc((size_t)NN * NN * 2);
    int* topk = (int*)alloc(NN * 10 * 4);
    int* nbr = (int*)alloc(NN * 10 * 4);
    float* tvals = (float*)alloc(NN * 10 * 4);
    int* hcols = (int*)alloc(NN * 50 * 4);
    float* hvals = (float*)alloc(NN * 50 * 4);

    hipMemsetAsync(d_ws, 0, zero_bytes, stream);

    normalize_kernel<1024><<<NN, 256, 0, stream>>>(t_g, tb, ss_t);
    normalize_kernel<512><<<NN, 256, 0, stream>>>(s_f, fb, ss_f);
    normalize_kernel<512><<<NN, 256, 0, stream>>>(s_g, gb, ss_g);

    gram_merged<<<1584, 256, 0, stream>>>(tb, fb, gb, ss_t, ss_f, ss_g, WP, Sf, Sg,
                                          rowsum_f, rowsum_g);

    topk_kernel<<<NN, 256, 0, stream>>>(WP, idx, topk);
    mutual_kernel<<<(NN * 10 + 255) / 256, 256, 0, stream>>>(topk, nbr, deg);
    tilda_kernel<<<(NN * 10 + 255) / 256, 256, 0, stream>>>(nbr, deg, tvals);
    hat_kernel<<<(NN * 5 + 255) / 256, 256, 0, stream>>>(topk, nbr, tvals, hcols, hvals);

    fused_dense_kernel<<<NN, 256, 0, stream>>>(Sf, Sg, WP, rowsum_f, rowsum_g, acc);
    sparse_kernel<<<NN / 4, 256, 0, stream>>>(Sf, Sg, hcols, hvals, rowsum_f, rowsum_g, acc);
    finalize_kernel<<<1, 64, 0, stream>>>(acc, out);
}